// Round 4
// baseline (585.029 us; speedup 1.0000x reference)
//
#include <hip/hip_runtime.h>

// ---------------------------------------------------------------------------
// ConvLSTMNet round 11:
//  - lstm: 2-wave blocks (128 thr), each wave owns 32 units (8 C-tiles =
//    4 gates x 2 subtiles, 48 MFMA/step). 440 blocks x 2 waves = 880 waves
//    -> every SIMD carries at most ONE wave (was 2 on the 184 busiest CUs).
//    Per-step wall drops from 2x wave-issue (+ barrier straggle) to ~1x.
//    __launch_bounds__(128,1) allows the ~300-reg working set (unified
//    VGPR+AGPR file) at 1 wave/SIMD. Same math, same order -> same absmax.
//  - FC: unchanged from R10 (atomic split-K + fc_init, 233 us measured).
// ---------------------------------------------------------------------------

#define T_STEPS 256
#define PIX 55
#define MT 16          // sequences per tile (MFMA N-dim)
#define TILES 110      // 1760 / 16
#define LOG2E 1.4426950408889634f
#define FC_SUB 128     // kc per LDS stage
#define FC_GRP 16      // W pipeline depth

typedef float f32x4 __attribute__((ext_vector_type(4)));
typedef __bf16 bf16x8 __attribute__((ext_vector_type(8)));
typedef __bf16 bf16x4 __attribute__((ext_vector_type(4)));

__global__ __launch_bounds__(128, 1) void lstm_kernel(
    const float* __restrict__ x1, const float* __restrict__ x2,
    const float* __restrict__ wx1, const float* __restrict__ wh1,
    const float* __restrict__ bx1, const float* __restrict__ bh1,
    const float* __restrict__ wx2, const float* __restrict__ wh2,
    const float* __restrict__ bx2, const float* __restrict__ bh2,
    float* __restrict__ feat)   // [64][7040]: row sub*32+b, col (cell*64+u)*55+p
{
    int bid  = blockIdx.x;            // 0..439
    int tile = bid % TILES;
    int cc   = bid / TILES;           // 0..3
    int sub  = cc >> 1, cell = cc & 1;
    const float* x  = sub  ? x2  : x1;
    const float* wx = cell ? wx2 : wx1;
    const float* wh = cell ? wh2 : wh1;
    const float* bx = cell ? bx2 : bx1;
    const float* bh = cell ? bh2 : bh1;

    int tid  = threadIdx.x;           // 0..127
    int wv   = tid >> 6;              // wave id (0..1): owns units 32wv..32wv+31
    int l    = tid & 63;
    int quad = l >> 4;
    int c16  = l & 15;

    __shared__ float xl[MT * 514];                        // [seq][t*2+c], pad 514
    __shared__ __align__(16) __bf16 hb[2][2][MT][72];     // [buf][hi/lo][seq][u pad72]

    // ---- stage x for this block's 16 sequences (all 256 steps) ----
    {
        int seq0 = tile * MT;
        for (int i = 0; i < 64; ++i) {
            int idx = tid + 128 * i;          // m*512 + t*2 + c
            int m = idx >> 9;
            int tc = idx & 511;
            int t = tc >> 1, c = tc & 1;
            int seq = seq0 + m;
            int b = seq / PIX, p = seq % PIX;
            xl[m * 514 + tc] = x[((b * T_STEPS + t) * 2 + c) * PIX + p];
        }
    }
    // ---- zero h buffers ----
    {
        __bf16* hz = &hb[0][0][0][0];
        for (int i = tid; i < 2 * 2 * MT * 72; i += 128) hz[i] = (__bf16)0.0f;
    }

    // ---- W as A-operand fragments (hi+lo), per gate, subtile & K-slab ----
    bf16x8 Whi[4][2][2], Wlo[4][2][2];     // [gate][subtile][kslab]
    float btot[4][2][4], wxa[4][2][4], wxb[4][2][4];
#pragma unroll
    for (int g = 0; g < 4; ++g) {
#pragma unroll
        for (int s = 0; s < 2; ++s) {
            int col = 64 * g + 32 * wv + 16 * s + c16;
#pragma unroll
            for (int r = 0; r < 4; ++r) {
                int u = 64 * g + 32 * wv + 16 * s + 4 * quad + r;
                btot[g][s][r] = bx[u] + bh[u];
                wxa[g][s][r]  = wx[u];
                wxb[g][s][r]  = wx[256 + u];
            }
#pragma unroll
            for (int q = 0; q < 2; ++q) {
#pragma unroll
                for (int j = 0; j < 8; ++j) {
                    int k = 32 * q + 8 * quad + j;
                    float wvv = wh[k * 256 + col];
                    __bf16 hi = (__bf16)wvv;
                    Whi[g][s][q][j] = hi;
                    Wlo[g][s][q][j] = (__bf16)(wvv - (float)hi);
                }
            }
        }
    }

    float cst[2][4]  = {{0.f, 0.f, 0.f, 0.f}, {0.f, 0.f, 0.f, 0.f}};
    float hfin[2][4] = {{0.f, 0.f, 0.f, 0.f}, {0.f, 0.f, 0.f, 0.f}};

    __syncthreads();
    float2 xv = *(const float2*)&xl[c16 * 514 + (cell ? (T_STEPS - 1) : 0) * 2];

#pragma unroll 2
    for (int t = 0; t < T_STEPS; ++t) {
        int rb = t & 1, wb = rb ^ 1;

        bf16x8 Bh[2], Bl[2];
#pragma unroll
        for (int q = 0; q < 2; ++q) {
            Bh[q] = *(const bf16x8*)&hb[rb][0][c16][32 * q + 8 * quad];
            Bl[q] = *(const bf16x8*)&hb[rb][1][c16][32 * q + 8 * quad];
        }

        f32x4 acc[4][2];
#pragma unroll
        for (int g = 0; g < 4; ++g)
#pragma unroll
            for (int s = 0; s < 2; ++s)
#pragma unroll
                for (int r = 0; r < 4; ++r)
                    acc[g][s][r] = fmaf(xv.y, wxb[g][s][r],
                                        fmaf(xv.x, wxa[g][s][r], btot[g][s][r]));

        // product-major: 6 rounds x 8 tiles -> 8-way dependent-chain ILP.
#pragma unroll
        for (int g = 0; g < 4; ++g)
#pragma unroll
            for (int s = 0; s < 2; ++s)
                acc[g][s] = __builtin_amdgcn_mfma_f32_16x16x32_bf16(Whi[g][s][0], Bh[0], acc[g][s], 0, 0, 0);
#pragma unroll
        for (int g = 0; g < 4; ++g)
#pragma unroll
            for (int s = 0; s < 2; ++s)
                acc[g][s] = __builtin_amdgcn_mfma_f32_16x16x32_bf16(Whi[g][s][1], Bh[1], acc[g][s], 0, 0, 0);
#pragma unroll
        for (int g = 0; g < 4; ++g)
#pragma unroll
            for (int s = 0; s < 2; ++s)
                acc[g][s] = __builtin_amdgcn_mfma_f32_16x16x32_bf16(Wlo[g][s][0], Bh[0], acc[g][s], 0, 0, 0);
#pragma unroll
        for (int g = 0; g < 4; ++g)
#pragma unroll
            for (int s = 0; s < 2; ++s)
                acc[g][s] = __builtin_amdgcn_mfma_f32_16x16x32_bf16(Wlo[g][s][1], Bh[1], acc[g][s], 0, 0, 0);
#pragma unroll
        for (int g = 0; g < 4; ++g)
#pragma unroll
            for (int s = 0; s < 2; ++s)
                acc[g][s] = __builtin_amdgcn_mfma_f32_16x16x32_bf16(Whi[g][s][0], Bl[0], acc[g][s], 0, 0, 0);
#pragma unroll
        for (int g = 0; g < 4; ++g)
#pragma unroll
            for (int s = 0; s < 2; ++s)
                acc[g][s] = __builtin_amdgcn_mfma_f32_16x16x32_bf16(Whi[g][s][1], Bl[1], acc[g][s], 0, 0, 0);

        // exp phase: 32 independent transcendentals, streamed
        float ei[2][4], ef[2][4], eo[2][4], eg[2][4];
#pragma unroll
        for (int s = 0; s < 2; ++s)
#pragma unroll
            for (int r = 0; r < 4; ++r) {
                ei[s][r] = __builtin_amdgcn_exp2f(-LOG2E * acc[0][s][r]);
                ef[s][r] = __builtin_amdgcn_exp2f(-LOG2E * acc[1][s][r]);
                eo[s][r] = __builtin_amdgcn_exp2f(-LOG2E * acc[2][s][r]);
                eg[s][r] = __builtin_amdgcn_exp2f(-2.0f * LOG2E * acc[3][s][r]);
            }

        bf16x4 ph[2], pl[2];
#pragma unroll
        for (int s = 0; s < 2; ++s)
#pragma unroll
            for (int r = 0; r < 4; ++r) {
                float sf  = __builtin_amdgcn_rcpf(1.0f + ef[s][r]);
                float itg = (1.0f - eg[s][r]) *
                            __builtin_amdgcn_rcpf((1.0f + ei[s][r]) * (1.0f + eg[s][r]));
                float c   = fmaf(sf, cst[s][r], itg);
                cst[s][r] = c;
                float ec = __builtin_amdgcn_exp2f(-2.0f * LOG2E * c);
                float h  = (1.0f - ec) * __builtin_amdgcn_rcpf((1.0f + eo[s][r]) * (1.0f + ec));
                hfin[s][r] = h;
                __bf16 hi = (__bf16)h;
                ph[s][r] = hi;
                pl[s][r] = (__bf16)(h - (float)hi);
            }
#pragma unroll
        for (int s = 0; s < 2; ++s) {
            *(bf16x4*)&hb[wb][0][c16][32 * wv + 16 * s + 4 * quad] = ph[s];
            *(bf16x4*)&hb[wb][1][c16][32 * wv + 16 * s + 4 * quad] = pl[s];
        }

        // prefetch next step's x contribution BEFORE the barrier
        {
            int txn = (cell ? (T_STEPS - 2 - t) : (t + 1)) & 255;
            xv = *(const float2*)&xl[c16 * 514 + txn * 2];
        }
        __syncthreads();
    }

    {
        int seq = tile * MT + c16;
        int b = seq / PIX, p = seq % PIX;
#pragma unroll
        for (int s = 0; s < 2; ++s)
#pragma unroll
            for (int r = 0; r < 4; ++r) {
                int u = 32 * wv + 16 * s + 4 * quad + r;
                feat[(size_t)(sub * 32 + b) * 7040 + (cell * 64 + u) * PIX + p] = hfin[s][r];
            }
    }
}

// ---------------------------------------------------------------------------
// fc_init: pre-fill all four FC outputs with their bias rows (replaces the
// four fc_reduce launches; fc_gemm then accumulates atomically).
// Layout: t1[64][3400], t2[64][1000], t3[64][500], o[64][50].
// ---------------------------------------------------------------------------
__global__ __launch_bounds__(256) void fc_init(
    const float* __restrict__ b2, const float* __restrict__ b3,
    const float* __restrict__ b4, const float* __restrict__ b5,
    float* __restrict__ t1, float* __restrict__ t2,
    float* __restrict__ t3, float* __restrict__ o)
{
    int i = blockIdx.x * 256 + threadIdx.x;
    const int n1 = 64 * 3400, n2 = 64 * 1000, n3 = 64 * 500, n4 = 64 * 50;
    if (i < n1) { t1[i] = b2[i % 3400]; return; }
    i -= n1;
    if (i < n2) { t2[i] = b3[i % 1000]; return; }
    i -= n2;
    if (i < n3) { t3[i] = b4[i % 500]; return; }
    i -= n3;
    if (i < n4) { o[i] = b5[i % 50]; }
}

// ---------------------------------------------------------------------------
// FC slim v3 (atomic split-K): out[64][N] += A[64][kchunk] @ W[kchunk][N].
// Block = 64 m x 64 n. Lane owns ONE n (acc[16] = 16 VGPR). Wave w -> rows
// 16w..16w+15 (broadcast b128 A reads). kcur==128 path fully unrolled (8x16
// static groups -> scheduler pipelines W loads across groups). Accumulation
// into bias-pre-initialized out via native f32 atomics.
// ---------------------------------------------------------------------------
__global__ __launch_bounds__(256) void fc_gemm(const float* __restrict__ A,
                                               const float* __restrict__ W,
                                               float* __restrict__ out,
                                               int K, int N, int kchunk) {
    __shared__ __align__(16) float al[FC_SUB * 68];   // [kc][m pad68]
    int tid = threadIdx.x;
    int l   = tid & 63;
    int wv  = tid >> 6;
    int k0   = blockIdx.y * kchunk;
    int kend = min(K, k0 + kchunk);

    int n  = blockIdx.x * 64 + l;
    int ne = min(n, N - 1);                // clamped load index (stores guarded)

    float acc[16];
#pragma unroll
    for (int i = 0; i < 16; ++i) acc[i] = 0.0f;

    for (int ks = k0; ks < kend; ks += FC_SUB) {
        int kcur = min(FC_SUB, kend - ks);
        __syncthreads();                   // protect al reuse
        // ---- stage A[0:64][ks:ks+kcur]: 32 independent coalesced loads ----
        if (kcur == FC_SUB) {
#pragma unroll
            for (int i = 0; i < 32; ++i) {
                int idx = tid + 256 * i;       // m = idx>>7, kc = idx&127
                int m = idx >> 7, kc = idx & 127;
                al[kc * 68 + m] = A[(size_t)m * K + ks + kc];
            }
        } else {
#pragma unroll
            for (int i = 0; i < 32; ++i) {
                int idx = tid + 256 * i;
                int m = idx >> 7, kc = idx & 127;
                if (kc < kcur) al[kc * 68 + m] = A[(size_t)m * K + ks + kc];
            }
        }
        __syncthreads();

        const float* wr = W + (size_t)ks * N + ne;
        if (kcur == FC_SUB) {
            // hot path: 8 static groups of 16, fully unrolled
#pragma unroll
            for (int g8 = 0; g8 < FC_SUB / FC_GRP; ++g8) {
                float wbuf[FC_GRP];
#pragma unroll
                for (int j = 0; j < FC_GRP; ++j)
                    wbuf[j] = wr[(size_t)(g8 * FC_GRP + j) * N];
#pragma unroll
                for (int j = 0; j < FC_GRP; ++j) {
                    const float4* ap = (const float4*)&al[(g8 * FC_GRP + j) * 68 + 16 * wv];
#pragma unroll
                    for (int i = 0; i < 4; ++i) {
                        float4 a = ap[i];
                        acc[4 * i + 0] = fmaf(a.x, wbuf[j], acc[4 * i + 0]);
                        acc[4 * i + 1] = fmaf(a.y, wbuf[j], acc[4 * i + 1]);
                        acc[4 * i + 2] = fmaf(a.z, wbuf[j], acc[4 * i + 2]);
                        acc[4 * i + 3] = fmaf(a.w, wbuf[j], acc[4 * i + 3]);
                    }
                }
            }
        } else {
            int kc0 = 0;
            for (; kc0 + FC_GRP <= kcur; kc0 += FC_GRP) {
                float wbuf[FC_GRP];
#pragma unroll
                for (int j = 0; j < FC_GRP; ++j)
                    wbuf[j] = wr[(size_t)(kc0 + j) * N];
#pragma unroll
                for (int j = 0; j < FC_GRP; ++j) {
                    const float4* ap = (const float4*)&al[(kc0 + j) * 68 + 16 * wv];
#pragma unroll
                    for (int i = 0; i < 4; ++i) {
                        float4 a = ap[i];
                        acc[4 * i + 0] = fmaf(a.x, wbuf[j], acc[4 * i + 0]);
                        acc[4 * i + 1] = fmaf(a.y, wbuf[j], acc[4 * i + 1]);
                        acc[4 * i + 2] = fmaf(a.z, wbuf[j], acc[4 * i + 2]);
                        acc[4 * i + 3] = fmaf(a.w, wbuf[j], acc[4 * i + 3]);
                    }
                }
            }
            for (; kc0 < kcur; ++kc0) {
                float wvv = wr[(size_t)kc0 * N];
                const float4* ap = (const float4*)&al[kc0 * 68 + 16 * wv];
#pragma unroll
                for (int i = 0; i < 4; ++i) {
                    float4 a = ap[i];
                    acc[4 * i + 0] = fmaf(a.x, wvv, acc[4 * i + 0]);
                    acc[4 * i + 1] = fmaf(a.y, wvv, acc[4 * i + 1]);
                    acc[4 * i + 2] = fmaf(a.z, wvv, acc[4 * i + 2]);
                    acc[4 * i + 3] = fmaf(a.w, wvv, acc[4 * i + 3]);
                }
            }
        }
    }

    if (n < N) {
        float* pr = out + n;
#pragma unroll
        for (int i = 0; i < 16; ++i)
            unsafeAtomicAdd(&pr[(size_t)(16 * wv + i) * N], acc[i]);
    }
}

extern "C" void kernel_launch(void* const* d_in, const int* in_sizes, int n_in,
                              void* d_out, int out_size, void* d_ws, size_t ws_size,
                              hipStream_t stream) {
    const float* x1  = (const float*)d_in[0];
    const float* x2  = (const float*)d_in[1];
    const float* wx1 = (const float*)d_in[2];
    const float* wh1 = (const float*)d_in[3];
    const float* bx1 = (const float*)d_in[4];
    const float* bh1 = (const float*)d_in[5];
    const float* wx2 = (const float*)d_in[6];
    const float* wh2 = (const float*)d_in[7];
    const float* bx2 = (const float*)d_in[8];
    const float* bh2 = (const float*)d_in[9];
    const float* fw2 = (const float*)d_in[10];
    const float* fb2 = (const float*)d_in[11];
    const float* fw3 = (const float*)d_in[12];
    const float* fb3 = (const float*)d_in[13];
    const float* fw4 = (const float*)d_in[14];
    const float* fb4 = (const float*)d_in[15];
    const float* fw5 = (const float*)d_in[16];
    const float* fb5 = (const float*)d_in[17];

    char* ws = (char*)d_ws;
    float* feat = (float*)ws;                                   // [64][7040]
    float* t1   = feat + (size_t)64 * 7040;                     // [64][3400]
    float* t2   = t1   + (size_t)64 * 3400;                     // [64][1000]
    float* t3   = t2   + (size_t)64 * 1000;                     // [64][500]
    float* o    = (float*)d_out;                                // [64][50]

    // bias pre-fill for all four FC outputs (316800 elems)
    fc_init<<<dim3(1238), dim3(256), 0, stream>>>(fb2, fb3, fb4, fb5, t1, t2, t3, o);

    lstm_kernel<<<dim3(440), dim3(128), 0, stream>>>(
        x1, x2, wx1, wh1, bx1, bh1, wx2, wh2, bx2, bh2, feat);

    // atomic split-K GEMMs (out pre-filled with bias)
    fc_gemm<<<dim3(54, 28), dim3(256), 0, stream>>>(feat, fw2, t1, 7040, 3400, 256);
    fc_gemm<<<dim3(16, 54), dim3(256), 0, stream>>>(t1, fw3, t2, 3400, 1000, 64);
    fc_gemm<<<dim3(8, 16), dim3(256), 0, stream>>>(t2, fw4, t3, 1000, 500, 64);
    fc_gemm<<<dim3(1, 16), dim3(256), 0, stream>>>(t3, fw5, o, 500, 50, 32);
}

// Round 5
// 569.314 us; speedup vs baseline: 1.0276x; 1.0276x over previous
//
#include <hip/hip_runtime.h>

// ---------------------------------------------------------------------------
// ConvLSTMNet round 12:
//  - lstm: exact R10 revert (best measured 317.3 us, 80 VGPR, 4-wave blocks).
//  - FC: software-pipelined W loads. 32-deep groups, register double-buffer:
//    group g+1's 32 loads issue BEFORE group g's FMAs consume (compiler emits
//    counted vmcnt instead of drain-0 every 16 loads). Load latency (~600-900
//    cyc HBM) hides under 1024 cyc of FMA per group. Accumulation order is
//    still k-ascending -> absmax identical. Atomic split-K + fc_init kept.
// ---------------------------------------------------------------------------

#define T_STEPS 256
#define PIX 55
#define MT 16          // sequences per tile (MFMA N-dim)
#define TILES 110      // 1760 / 16
#define LOG2E 1.4426950408889634f
#define FC_SUB 128     // kc per LDS stage
#define FC_GRP 16      // W pipeline depth (remainder path)

typedef float f32x4 __attribute__((ext_vector_type(4)));
typedef __bf16 bf16x8 __attribute__((ext_vector_type(8)));
typedef __bf16 bf16x4 __attribute__((ext_vector_type(4)));

__global__ __launch_bounds__(256) void lstm_kernel(
    const float* __restrict__ x1, const float* __restrict__ x2,
    const float* __restrict__ wx1, const float* __restrict__ wh1,
    const float* __restrict__ bx1, const float* __restrict__ bh1,
    const float* __restrict__ wx2, const float* __restrict__ wh2,
    const float* __restrict__ bx2, const float* __restrict__ bh2,
    float* __restrict__ feat)   // [64][7040]: row sub*32+b, col (cell*64+u)*55+p
{
    int bid  = blockIdx.x;            // 0..439
    int tile = bid % TILES;
    int cc   = bid / TILES;           // 0..3
    int sub  = cc >> 1, cell = cc & 1;
    const float* x  = sub  ? x2  : x1;
    const float* wx = cell ? wx2 : wx1;
    const float* wh = cell ? wh2 : wh1;
    const float* bx = cell ? bx2 : bx1;
    const float* bh = cell ? bh2 : bh1;

    int tid  = threadIdx.x;
    int w    = tid >> 6;              // wave id = unit subtile (units 16w..16w+15)
    int l    = tid & 63;
    int quad = l >> 4;
    int c16  = l & 15;

    __shared__ float xl[MT * 514];                        // [seq][t*2+c], pad 514
    __shared__ __align__(16) __bf16 hb[2][2][MT][72];     // [buf][hi/lo][seq][u pad72]

    // ---- stage x for this block's 16 sequences (all 256 steps) ----
    {
        int seq0 = tile * MT;
        for (int i = 0; i < 32; ++i) {
            int idx = tid + 256 * i;          // m*512 + t*2 + c
            int m = idx >> 9;
            int tc = idx & 511;
            int t = tc >> 1, c = tc & 1;
            int seq = seq0 + m;
            int b = seq / PIX, p = seq % PIX;
            xl[m * 514 + tc] = x[((b * T_STEPS + t) * 2 + c) * PIX + p];
        }
    }
    // ---- zero h buffers ----
    {
        __bf16* hz = &hb[0][0][0][0];
        for (int i = tid; i < 2 * 2 * MT * 72; i += 256) hz[i] = (__bf16)0.0f;
    }

    // ---- W as A-operand fragments (hi+lo), per gate & K-slab ----
    bf16x8 Whi[4][2], Wlo[4][2];
    float btot[4][4], wxa[4][4], wxb[4][4];
#pragma unroll
    for (int g = 0; g < 4; ++g) {
        int col = 64 * g + 16 * w + c16;
#pragma unroll
        for (int r = 0; r < 4; ++r) {
            int u = 64 * g + 16 * w + 4 * quad + r;   // this thread's C-row units
            btot[g][r] = bx[u] + bh[u];
            wxa[g][r]  = wx[u];
            wxb[g][r]  = wx[256 + u];
        }
#pragma unroll
        for (int q = 0; q < 2; ++q) {
#pragma unroll
            for (int j = 0; j < 8; ++j) {
                int k = 32 * q + 8 * quad + j;
                float wv = wh[k * 256 + col];
                __bf16 hi = (__bf16)wv;
                Whi[g][q][j] = hi;
                Wlo[g][q][j] = (__bf16)(wv - (float)hi);
            }
        }
    }

    float cst[4]  = {0.f, 0.f, 0.f, 0.f};
    float hfin[4] = {0.f, 0.f, 0.f, 0.f};

    // xv for step 0 (xl is read-only after staging; prefetched pre-barrier
    // for every later step)
    __syncthreads();
    float2 xv = *(const float2*)&xl[c16 * 514 + (cell ? (T_STEPS - 1) : 0) * 2];

#pragma unroll 2
    for (int t = 0; t < T_STEPS; ++t) {
        int rb = t & 1, wb = rb ^ 1;

        bf16x8 Bh[2], Bl[2];
#pragma unroll
        for (int q = 0; q < 2; ++q) {
            Bh[q] = *(const bf16x8*)&hb[rb][0][c16][32 * q + 8 * quad];
            Bl[q] = *(const bf16x8*)&hb[rb][1][c16][32 * q + 8 * quad];
        }

        f32x4 acc[4];
#pragma unroll
        for (int g = 0; g < 4; ++g) {
#pragma unroll
            for (int r = 0; r < 4; ++r)
                acc[g][r] = fmaf(xv.y, wxb[g][r], fmaf(xv.x, wxa[g][r], btot[g][r]));
        }
        // product-major: 6 rounds x 4 gates -> 4-way dependent-chain ILP.
#pragma unroll
        for (int g = 0; g < 4; ++g)
            acc[g] = __builtin_amdgcn_mfma_f32_16x16x32_bf16(Whi[g][0], Bh[0], acc[g], 0, 0, 0);
#pragma unroll
        for (int g = 0; g < 4; ++g)
            acc[g] = __builtin_amdgcn_mfma_f32_16x16x32_bf16(Whi[g][1], Bh[1], acc[g], 0, 0, 0);
#pragma unroll
        for (int g = 0; g < 4; ++g)
            acc[g] = __builtin_amdgcn_mfma_f32_16x16x32_bf16(Wlo[g][0], Bh[0], acc[g], 0, 0, 0);
#pragma unroll
        for (int g = 0; g < 4; ++g)
            acc[g] = __builtin_amdgcn_mfma_f32_16x16x32_bf16(Wlo[g][1], Bh[1], acc[g], 0, 0, 0);
#pragma unroll
        for (int g = 0; g < 4; ++g)
            acc[g] = __builtin_amdgcn_mfma_f32_16x16x32_bf16(Whi[g][0], Bl[0], acc[g], 0, 0, 0);
#pragma unroll
        for (int g = 0; g < 4; ++g)
            acc[g] = __builtin_amdgcn_mfma_f32_16x16x32_bf16(Whi[g][1], Bl[1], acc[g], 0, 0, 0);

        // exp phase: 16 independent transcendentals, streamed
        float ei[4], ef[4], eo[4], eg[4];
#pragma unroll
        for (int r = 0; r < 4; ++r) {
            ei[r] = __builtin_amdgcn_exp2f(-LOG2E * acc[0][r]);
            ef[r] = __builtin_amdgcn_exp2f(-LOG2E * acc[1][r]);
            eo[r] = __builtin_amdgcn_exp2f(-LOG2E * acc[2][r]);
            eg[r] = __builtin_amdgcn_exp2f(-2.0f * LOG2E * acc[3][r]);
        }

        bf16x4 ph, pl;
#pragma unroll
        for (int r = 0; r < 4; ++r) {
            float sf  = __builtin_amdgcn_rcpf(1.0f + ef[r]);
            float itg = (1.0f - eg[r]) * __builtin_amdgcn_rcpf((1.0f + ei[r]) * (1.0f + eg[r]));
            float c   = fmaf(sf, cst[r], itg);
            cst[r] = c;
            float ec = __builtin_amdgcn_exp2f(-2.0f * LOG2E * c);
            float h  = (1.0f - ec) * __builtin_amdgcn_rcpf((1.0f + eo[r]) * (1.0f + ec));
            hfin[r] = h;
            __bf16 hi = (__bf16)h;
            ph[r] = hi;
            pl[r] = (__bf16)(h - (float)hi);
        }
        *(bf16x4*)&hb[wb][0][c16][16 * w + 4 * quad] = ph;
        *(bf16x4*)&hb[wb][1][c16][16 * w + 4 * quad] = pl;

        // prefetch next step's x contribution BEFORE the barrier (xl is
        // read-only; &255 keeps the dead last-iteration index in-bounds)
        {
            int txn = (cell ? (T_STEPS - 2 - t) : (t + 1)) & 255;
            xv = *(const float2*)&xl[c16 * 514 + txn * 2];
        }
        __syncthreads();
    }

    {
        int seq = tile * MT + c16;
        int b = seq / PIX, p = seq % PIX;
#pragma unroll
        for (int r = 0; r < 4; ++r) {
            int u = 16 * w + 4 * quad + r;
            feat[(size_t)(sub * 32 + b) * 7040 + (cell * 64 + u) * PIX + p] = hfin[r];
        }
    }
}

// ---------------------------------------------------------------------------
// fc_init: pre-fill all four FC outputs with their bias rows (replaces the
// four fc_reduce launches; fc_gemm then accumulates atomically).
// Layout: t1[64][3400], t2[64][1000], t3[64][500], o[64][50].
// ---------------------------------------------------------------------------
__global__ __launch_bounds__(256) void fc_init(
    const float* __restrict__ b2, const float* __restrict__ b3,
    const float* __restrict__ b4, const float* __restrict__ b5,
    float* __restrict__ t1, float* __restrict__ t2,
    float* __restrict__ t3, float* __restrict__ o)
{
    int i = blockIdx.x * 256 + threadIdx.x;
    const int n1 = 64 * 3400, n2 = 64 * 1000, n3 = 64 * 500, n4 = 64 * 50;
    if (i < n1) { t1[i] = b2[i % 3400]; return; }
    i -= n1;
    if (i < n2) { t2[i] = b3[i % 1000]; return; }
    i -= n2;
    if (i < n3) { t3[i] = b4[i % 500]; return; }
    i -= n3;
    if (i < n4) { o[i] = b5[i % 50]; }
}

// 16-FMA bundle: lane's 16 m-rows against one W scalar (k = KB + j)
#define FC_FMA16(KB, j, WS)                                                  \
    {                                                                        \
        const float4* ap_ = (const float4*)&al[((KB) + (j)) * 68 + 16 * wv]; \
        _Pragma("unroll")                                                    \
        for (int i_ = 0; i_ < 4; ++i_) {                                     \
            float4 a_ = ap_[i_];                                             \
            acc[4 * i_ + 0] = fmaf(a_.x, (WS), acc[4 * i_ + 0]);             \
            acc[4 * i_ + 1] = fmaf(a_.y, (WS), acc[4 * i_ + 1]);             \
            acc[4 * i_ + 2] = fmaf(a_.z, (WS), acc[4 * i_ + 2]);             \
            acc[4 * i_ + 3] = fmaf(a_.w, (WS), acc[4 * i_ + 3]);             \
        }                                                                    \
    }

// ---------------------------------------------------------------------------
// FC slim v4 (atomic split-K, pipelined W loads): out[64][N] +=
// A[64][kchunk] @ W[kchunk][N]. Block = 64 m x 64 n; lane owns ONE n.
// Hot paths (kcur 128/64): 32-deep load groups, register double-buffer --
// group g+1's loads issue before group g's FMAs, so the compiler emits
// counted vmcnt (loads stay in flight under ~1024 cyc of FMA) instead of
// a drain every 16 loads. k-ascending accumulation order preserved.
// ---------------------------------------------------------------------------
__global__ __launch_bounds__(256) void fc_gemm(const float* __restrict__ A,
                                               const float* __restrict__ W,
                                               float* __restrict__ out,
                                               int K, int N, int kchunk) {
    __shared__ __align__(16) float al[FC_SUB * 68];   // [kc][m pad68]
    int tid = threadIdx.x;
    int l   = tid & 63;
    int wv  = tid >> 6;
    int k0   = blockIdx.y * kchunk;
    int kend = min(K, k0 + kchunk);

    int n  = blockIdx.x * 64 + l;
    int ne = min(n, N - 1);                // clamped load index (stores guarded)

    float acc[16];
#pragma unroll
    for (int i = 0; i < 16; ++i) acc[i] = 0.0f;

    for (int ks = k0; ks < kend; ks += FC_SUB) {
        int kcur = min(FC_SUB, kend - ks);
        __syncthreads();                   // protect al reuse
        // ---- stage A[0:64][ks:ks+kcur]: 32 independent coalesced loads ----
        if (kcur == FC_SUB) {
#pragma unroll
            for (int i = 0; i < 32; ++i) {
                int idx = tid + 256 * i;       // m = idx>>7, kc = idx&127
                int m = idx >> 7, kc = idx & 127;
                al[kc * 68 + m] = A[(size_t)m * K + ks + kc];
            }
        } else {
#pragma unroll
            for (int i = 0; i < 32; ++i) {
                int idx = tid + 256 * i;
                int m = idx >> 7, kc = idx & 127;
                if (kc < kcur) al[kc * 68 + m] = A[(size_t)m * K + ks + kc];
            }
        }
        __syncthreads();

        const float* wr = W + (size_t)ks * N + ne;
        if (kcur == FC_SUB) {
            // ---- 128 kc: 4 groups of 32, double-buffered pipeline ----
            float wb0[32], wb1[32];
#pragma unroll
            for (int j = 0; j < 32; ++j) wb0[j] = wr[(size_t)j * N];
#pragma unroll
            for (int j = 0; j < 32; ++j) wb1[j] = wr[(size_t)(32 + j) * N];
#pragma unroll
            for (int j = 0; j < 32; ++j) FC_FMA16(0, j, wb0[j]);
#pragma unroll
            for (int j = 0; j < 32; ++j) wb0[j] = wr[(size_t)(64 + j) * N];
#pragma unroll
            for (int j = 0; j < 32; ++j) FC_FMA16(32, j, wb1[j]);
#pragma unroll
            for (int j = 0; j < 32; ++j) wb1[j] = wr[(size_t)(96 + j) * N];
#pragma unroll
            for (int j = 0; j < 32; ++j) FC_FMA16(64, j, wb0[j]);
#pragma unroll
            for (int j = 0; j < 32; ++j) FC_FMA16(96, j, wb1[j]);
        } else if (kcur == 64) {
            // ---- 64 kc: 2 groups of 32, pipelined ----
            float wb0[32], wb1[32];
#pragma unroll
            for (int j = 0; j < 32; ++j) wb0[j] = wr[(size_t)j * N];
#pragma unroll
            for (int j = 0; j < 32; ++j) wb1[j] = wr[(size_t)(32 + j) * N];
#pragma unroll
            for (int j = 0; j < 32; ++j) FC_FMA16(0, j, wb0[j]);
#pragma unroll
            for (int j = 0; j < 32; ++j) FC_FMA16(32, j, wb1[j]);
        } else {
            // ---- remainder (tails: kcur in {8,20,32,40}) ----
            int kc0 = 0;
            for (; kc0 + FC_GRP <= kcur; kc0 += FC_GRP) {
                float wbuf[FC_GRP];
#pragma unroll
                for (int j = 0; j < FC_GRP; ++j)
                    wbuf[j] = wr[(size_t)(kc0 + j) * N];
#pragma unroll
                for (int j = 0; j < FC_GRP; ++j) FC_FMA16(kc0, j, wbuf[j]);
            }
            for (; kc0 < kcur; ++kc0) {
                float wvv = wr[(size_t)kc0 * N];
                FC_FMA16(kc0, 0, wvv);
            }
        }
    }

    if (n < N) {
        float* pr = out + n;
#pragma unroll
        for (int i = 0; i < 16; ++i)
            unsafeAtomicAdd(&pr[(size_t)(16 * wv + i) * N], acc[i]);
    }
}

extern "C" void kernel_launch(void* const* d_in, const int* in_sizes, int n_in,
                              void* d_out, int out_size, void* d_ws, size_t ws_size,
                              hipStream_t stream) {
    const float* x1  = (const float*)d_in[0];
    const float* x2  = (const float*)d_in[1];
    const float* wx1 = (const float*)d_in[2];
    const float* wh1 = (const float*)d_in[3];
    const float* bx1 = (const float*)d_in[4];
    const float* bh1 = (const float*)d_in[5];
    const float* wx2 = (const float*)d_in[6];
    const float* wh2 = (const float*)d_in[7];
    const float* bx2 = (const float*)d_in[8];
    const float* bh2 = (const float*)d_in[9];
    const float* fw2 = (const float*)d_in[10];
    const float* fb2 = (const float*)d_in[11];
    const float* fw3 = (const float*)d_in[12];
    const float* fb3 = (const float*)d_in[13];
    const float* fw4 = (const float*)d_in[14];
    const float* fb4 = (const float*)d_in[15];
    const float* fw5 = (const float*)d_in[16];
    const float* fb5 = (const float*)d_in[17];

    char* ws = (char*)d_ws;
    float* feat = (float*)ws;                                   // [64][7040]
    float* t1   = feat + (size_t)64 * 7040;                     // [64][3400]
    float* t2   = t1   + (size_t)64 * 3400;                     // [64][1000]
    float* t3   = t2   + (size_t)64 * 1000;                     // [64][500]
    float* o    = (float*)d_out;                                // [64][50]

    // bias pre-fill for all four FC outputs (316800 elems)
    fc_init<<<dim3(1238), dim3(256), 0, stream>>>(fb2, fb3, fb4, fb5, t1, t2, t3, o);

    lstm_kernel<<<dim3(440), dim3(256), 0, stream>>>(
        x1, x2, wx1, wh1, bx1, bh1, wx2, wh2, bx2, bh2, feat);

    // atomic split-K GEMMs (out pre-filled with bias)
    fc_gemm<<<dim3(54, 28), dim3(256), 0, stream>>>(feat, fw2, t1, 7040, 3400, 256);
    fc_gemm<<<dim3(16, 54), dim3(256), 0, stream>>>(t1, fw3, t2, 3400, 1000, 64);
    fc_gemm<<<dim3(8, 16), dim3(256), 0, stream>>>(t2, fw4, t3, 1000, 500, 64);
    fc_gemm<<<dim3(1, 16), dim3(256), 0, stream>>>(t3, fw5, o, 500, 50, 32);
}

// Round 6
// 565.735 us; speedup vs baseline: 1.0341x; 1.0063x over previous
//
#include <hip/hip_runtime.h>

// ---------------------------------------------------------------------------
// ConvLSTMNet round 13:
//  - lstm: exact R10 (best measured 317 us, 80 VGPR, 4-wave blocks).
//  - FC: R10 inner loop (16-deep compiler-scheduled groups — v4's explicit
//    32-deep pipeline regressed) with FC_SUB 128 -> 64: LDS 34.8 -> 17.4 KB
//    lifts occupancy 4 -> 8 blocks/CU (16 -> 32 waves/CU), doubling the TLP
//    that hides the ~900-cyc W-load latency. k-order unchanged -> absmax
//    identical. Atomic split-K + fc_init kept.
// ---------------------------------------------------------------------------

#define T_STEPS 256
#define PIX 55
#define MT 16          // sequences per tile (MFMA N-dim)
#define TILES 110      // 1760 / 16
#define LOG2E 1.4426950408889634f
#define FC_SUB 64      // kc per LDS stage (17.4 KB -> 8 blocks/CU)
#define FC_GRP 16      // W pipeline depth

typedef float f32x4 __attribute__((ext_vector_type(4)));
typedef __bf16 bf16x8 __attribute__((ext_vector_type(8)));
typedef __bf16 bf16x4 __attribute__((ext_vector_type(4)));

__global__ __launch_bounds__(256) void lstm_kernel(
    const float* __restrict__ x1, const float* __restrict__ x2,
    const float* __restrict__ wx1, const float* __restrict__ wh1,
    const float* __restrict__ bx1, const float* __restrict__ bh1,
    const float* __restrict__ wx2, const float* __restrict__ wh2,
    const float* __restrict__ bx2, const float* __restrict__ bh2,
    float* __restrict__ feat)   // [64][7040]: row sub*32+b, col (cell*64+u)*55+p
{
    int bid  = blockIdx.x;            // 0..439
    int tile = bid % TILES;
    int cc   = bid / TILES;           // 0..3
    int sub  = cc >> 1, cell = cc & 1;
    const float* x  = sub  ? x2  : x1;
    const float* wx = cell ? wx2 : wx1;
    const float* wh = cell ? wh2 : wh1;
    const float* bx = cell ? bx2 : bx1;
    const float* bh = cell ? bh2 : bh1;

    int tid  = threadIdx.x;
    int w    = tid >> 6;              // wave id = unit subtile (units 16w..16w+15)
    int l    = tid & 63;
    int quad = l >> 4;
    int c16  = l & 15;

    __shared__ float xl[MT * 514];                        // [seq][t*2+c], pad 514
    __shared__ __align__(16) __bf16 hb[2][2][MT][72];     // [buf][hi/lo][seq][u pad72]

    // ---- stage x for this block's 16 sequences (all 256 steps) ----
    {
        int seq0 = tile * MT;
        for (int i = 0; i < 32; ++i) {
            int idx = tid + 256 * i;          // m*512 + t*2 + c
            int m = idx >> 9;
            int tc = idx & 511;
            int t = tc >> 1, c = tc & 1;
            int seq = seq0 + m;
            int b = seq / PIX, p = seq % PIX;
            xl[m * 514 + tc] = x[((b * T_STEPS + t) * 2 + c) * PIX + p];
        }
    }
    // ---- zero h buffers ----
    {
        __bf16* hz = &hb[0][0][0][0];
        for (int i = tid; i < 2 * 2 * MT * 72; i += 256) hz[i] = (__bf16)0.0f;
    }

    // ---- W as A-operand fragments (hi+lo), per gate & K-slab ----
    bf16x8 Whi[4][2], Wlo[4][2];
    float btot[4][4], wxa[4][4], wxb[4][4];
#pragma unroll
    for (int g = 0; g < 4; ++g) {
        int col = 64 * g + 16 * w + c16;
#pragma unroll
        for (int r = 0; r < 4; ++r) {
            int u = 64 * g + 16 * w + 4 * quad + r;   // this thread's C-row units
            btot[g][r] = bx[u] + bh[u];
            wxa[g][r]  = wx[u];
            wxb[g][r]  = wx[256 + u];
        }
#pragma unroll
        for (int q = 0; q < 2; ++q) {
#pragma unroll
            for (int j = 0; j < 8; ++j) {
                int k = 32 * q + 8 * quad + j;
                float wv = wh[k * 256 + col];
                __bf16 hi = (__bf16)wv;
                Whi[g][q][j] = hi;
                Wlo[g][q][j] = (__bf16)(wv - (float)hi);
            }
        }
    }

    float cst[4]  = {0.f, 0.f, 0.f, 0.f};
    float hfin[4] = {0.f, 0.f, 0.f, 0.f};

    // xv for step 0 (xl is read-only after staging; prefetched pre-barrier
    // for every later step)
    __syncthreads();
    float2 xv = *(const float2*)&xl[c16 * 514 + (cell ? (T_STEPS - 1) : 0) * 2];

#pragma unroll 2
    for (int t = 0; t < T_STEPS; ++t) {
        int rb = t & 1, wb = rb ^ 1;

        bf16x8 Bh[2], Bl[2];
#pragma unroll
        for (int q = 0; q < 2; ++q) {
            Bh[q] = *(const bf16x8*)&hb[rb][0][c16][32 * q + 8 * quad];
            Bl[q] = *(const bf16x8*)&hb[rb][1][c16][32 * q + 8 * quad];
        }

        f32x4 acc[4];
#pragma unroll
        for (int g = 0; g < 4; ++g) {
#pragma unroll
            for (int r = 0; r < 4; ++r)
                acc[g][r] = fmaf(xv.y, wxb[g][r], fmaf(xv.x, wxa[g][r], btot[g][r]));
        }
        // product-major: 6 rounds x 4 gates -> 4-way dependent-chain ILP.
#pragma unroll
        for (int g = 0; g < 4; ++g)
            acc[g] = __builtin_amdgcn_mfma_f32_16x16x32_bf16(Whi[g][0], Bh[0], acc[g], 0, 0, 0);
#pragma unroll
        for (int g = 0; g < 4; ++g)
            acc[g] = __builtin_amdgcn_mfma_f32_16x16x32_bf16(Whi[g][1], Bh[1], acc[g], 0, 0, 0);
#pragma unroll
        for (int g = 0; g < 4; ++g)
            acc[g] = __builtin_amdgcn_mfma_f32_16x16x32_bf16(Wlo[g][0], Bh[0], acc[g], 0, 0, 0);
#pragma unroll
        for (int g = 0; g < 4; ++g)
            acc[g] = __builtin_amdgcn_mfma_f32_16x16x32_bf16(Wlo[g][1], Bh[1], acc[g], 0, 0, 0);
#pragma unroll
        for (int g = 0; g < 4; ++g)
            acc[g] = __builtin_amdgcn_mfma_f32_16x16x32_bf16(Whi[g][0], Bl[0], acc[g], 0, 0, 0);
#pragma unroll
        for (int g = 0; g < 4; ++g)
            acc[g] = __builtin_amdgcn_mfma_f32_16x16x32_bf16(Whi[g][1], Bl[1], acc[g], 0, 0, 0);

        // exp phase: 16 independent transcendentals, streamed
        float ei[4], ef[4], eo[4], eg[4];
#pragma unroll
        for (int r = 0; r < 4; ++r) {
            ei[r] = __builtin_amdgcn_exp2f(-LOG2E * acc[0][r]);
            ef[r] = __builtin_amdgcn_exp2f(-LOG2E * acc[1][r]);
            eo[r] = __builtin_amdgcn_exp2f(-LOG2E * acc[2][r]);
            eg[r] = __builtin_amdgcn_exp2f(-2.0f * LOG2E * acc[3][r]);
        }

        bf16x4 ph, pl;
#pragma unroll
        for (int r = 0; r < 4; ++r) {
            float sf  = __builtin_amdgcn_rcpf(1.0f + ef[r]);
            float itg = (1.0f - eg[r]) * __builtin_amdgcn_rcpf((1.0f + ei[r]) * (1.0f + eg[r]));
            float c   = fmaf(sf, cst[r], itg);
            cst[r] = c;
            float ec = __builtin_amdgcn_exp2f(-2.0f * LOG2E * c);
            float h  = (1.0f - ec) * __builtin_amdgcn_rcpf((1.0f + eo[r]) * (1.0f + ec));
            hfin[r] = h;
            __bf16 hi = (__bf16)h;
            ph[r] = hi;
            pl[r] = (__bf16)(h - (float)hi);
        }
        *(bf16x4*)&hb[wb][0][c16][16 * w + 4 * quad] = ph;
        *(bf16x4*)&hb[wb][1][c16][16 * w + 4 * quad] = pl;

        // prefetch next step's x contribution BEFORE the barrier (xl is
        // read-only; &255 keeps the dead last-iteration index in-bounds)
        {
            int txn = (cell ? (T_STEPS - 2 - t) : (t + 1)) & 255;
            xv = *(const float2*)&xl[c16 * 514 + txn * 2];
        }
        __syncthreads();
    }

    {
        int seq = tile * MT + c16;
        int b = seq / PIX, p = seq % PIX;
#pragma unroll
        for (int r = 0; r < 4; ++r) {
            int u = 16 * w + 4 * quad + r;
            feat[(size_t)(sub * 32 + b) * 7040 + (cell * 64 + u) * PIX + p] = hfin[r];
        }
    }
}

// ---------------------------------------------------------------------------
// fc_init: pre-fill all four FC outputs with their bias rows (replaces the
// four fc_reduce launches; fc_gemm then accumulates atomically).
// Layout: t1[64][3400], t2[64][1000], t3[64][500], o[64][50].
// ---------------------------------------------------------------------------
__global__ __launch_bounds__(256) void fc_init(
    const float* __restrict__ b2, const float* __restrict__ b3,
    const float* __restrict__ b4, const float* __restrict__ b5,
    float* __restrict__ t1, float* __restrict__ t2,
    float* __restrict__ t3, float* __restrict__ o)
{
    int i = blockIdx.x * 256 + threadIdx.x;
    const int n1 = 64 * 3400, n2 = 64 * 1000, n3 = 64 * 500, n4 = 64 * 50;
    if (i < n1) { t1[i] = b2[i % 3400]; return; }
    i -= n1;
    if (i < n2) { t2[i] = b3[i % 1000]; return; }
    i -= n2;
    if (i < n3) { t3[i] = b4[i % 500]; return; }
    i -= n3;
    if (i < n4) { o[i] = b5[i % 50]; }
}

// ---------------------------------------------------------------------------
// FC slim v5 (atomic split-K, high occupancy): out[64][N] +=
// A[64][kchunk] @ W[kchunk][N]. Block = 64 m x 64 n; lane owns ONE n
// (acc[16] = 16 VGPR). Wave w -> rows 16w..16w+15 (broadcast b128 A reads).
// FC_SUB=64: LDS 17.4 KB -> 8 blocks/CU (32 waves/CU) to hide W-load
// latency via TLP. Inner loop: 16-deep compiler-scheduled groups (proven).
// ---------------------------------------------------------------------------
__global__ __launch_bounds__(256) void fc_gemm(const float* __restrict__ A,
                                               const float* __restrict__ W,
                                               float* __restrict__ out,
                                               int K, int N, int kchunk) {
    __shared__ __align__(16) float al[FC_SUB * 68];   // [kc][m pad68]
    int tid = threadIdx.x;
    int l   = tid & 63;
    int wv  = tid >> 6;
    int k0   = blockIdx.y * kchunk;
    int kend = min(K, k0 + kchunk);

    int n  = blockIdx.x * 64 + l;
    int ne = min(n, N - 1);                // clamped load index (stores guarded)

    float acc[16];
#pragma unroll
    for (int i = 0; i < 16; ++i) acc[i] = 0.0f;

    for (int ks = k0; ks < kend; ks += FC_SUB) {
        int kcur = min(FC_SUB, kend - ks);
        __syncthreads();                   // protect al reuse
        // ---- stage A[0:64][ks:ks+kcur]: 16 independent coalesced loads ----
        if (kcur == FC_SUB) {
#pragma unroll
            for (int i = 0; i < 16; ++i) {
                int idx = tid + 256 * i;       // m = idx>>6, kc = idx&63
                int m = idx >> 6, kc = idx & 63;
                al[kc * 68 + m] = A[(size_t)m * K + ks + kc];
            }
        } else {
#pragma unroll
            for (int i = 0; i < 16; ++i) {
                int idx = tid + 256 * i;
                int m = idx >> 6, kc = idx & 63;
                if (kc < kcur) al[kc * 68 + m] = A[(size_t)m * K + ks + kc];
            }
        }
        __syncthreads();

        const float* wr = W + (size_t)ks * N + ne;
        if (kcur == FC_SUB) {
            // hot path: 4 static groups of 16, fully unrolled
#pragma unroll
            for (int g8 = 0; g8 < FC_SUB / FC_GRP; ++g8) {
                float wbuf[FC_GRP];
#pragma unroll
                for (int j = 0; j < FC_GRP; ++j)
                    wbuf[j] = wr[(size_t)(g8 * FC_GRP + j) * N];
#pragma unroll
                for (int j = 0; j < FC_GRP; ++j) {
                    const float4* ap = (const float4*)&al[(g8 * FC_GRP + j) * 68 + 16 * wv];
#pragma unroll
                    for (int i = 0; i < 4; ++i) {
                        float4 a = ap[i];
                        acc[4 * i + 0] = fmaf(a.x, wbuf[j], acc[4 * i + 0]);
                        acc[4 * i + 1] = fmaf(a.y, wbuf[j], acc[4 * i + 1]);
                        acc[4 * i + 2] = fmaf(a.z, wbuf[j], acc[4 * i + 2]);
                        acc[4 * i + 3] = fmaf(a.w, wbuf[j], acc[4 * i + 3]);
                    }
                }
            }
        } else {
            int kc0 = 0;
            for (; kc0 + FC_GRP <= kcur; kc0 += FC_GRP) {
                float wbuf[FC_GRP];
#pragma unroll
                for (int j = 0; j < FC_GRP; ++j)
                    wbuf[j] = wr[(size_t)(kc0 + j) * N];
#pragma unroll
                for (int j = 0; j < FC_GRP; ++j) {
                    const float4* ap = (const float4*)&al[(kc0 + j) * 68 + 16 * wv];
#pragma unroll
                    for (int i = 0; i < 4; ++i) {
                        float4 a = ap[i];
                        acc[4 * i + 0] = fmaf(a.x, wbuf[j], acc[4 * i + 0]);
                        acc[4 * i + 1] = fmaf(a.y, wbuf[j], acc[4 * i + 1]);
                        acc[4 * i + 2] = fmaf(a.z, wbuf[j], acc[4 * i + 2]);
                        acc[4 * i + 3] = fmaf(a.w, wbuf[j], acc[4 * i + 3]);
                    }
                }
            }
            for (; kc0 < kcur; ++kc0) {
                float wvv = wr[(size_t)kc0 * N];
                const float4* ap = (const float4*)&al[kc0 * 68 + 16 * wv];
#pragma unroll
                for (int i = 0; i < 4; ++i) {
                    float4 a = ap[i];
                    acc[4 * i + 0] = fmaf(a.x, wvv, acc[4 * i + 0]);
                    acc[4 * i + 1] = fmaf(a.y, wvv, acc[4 * i + 1]);
                    acc[4 * i + 2] = fmaf(a.z, wvv, acc[4 * i + 2]);
                    acc[4 * i + 3] = fmaf(a.w, wvv, acc[4 * i + 3]);
                }
            }
        }
    }

    if (n < N) {
        float* pr = out + n;
#pragma unroll
        for (int i = 0; i < 16; ++i)
            unsafeAtomicAdd(&pr[(size_t)(16 * wv + i) * N], acc[i]);
    }
}

extern "C" void kernel_launch(void* const* d_in, const int* in_sizes, int n_in,
                              void* d_out, int out_size, void* d_ws, size_t ws_size,
                              hipStream_t stream) {
    const float* x1  = (const float*)d_in[0];
    const float* x2  = (const float*)d_in[1];
    const float* wx1 = (const float*)d_in[2];
    const float* wh1 = (const float*)d_in[3];
    const float* bx1 = (const float*)d_in[4];
    const float* bh1 = (const float*)d_in[5];
    const float* wx2 = (const float*)d_in[6];
    const float* wh2 = (const float*)d_in[7];
    const float* bx2 = (const float*)d_in[8];
    const float* bh2 = (const float*)d_in[9];
    const float* fw2 = (const float*)d_in[10];
    const float* fb2 = (const float*)d_in[11];
    const float* fw3 = (const float*)d_in[12];
    const float* fb3 = (const float*)d_in[13];
    const float* fw4 = (const float*)d_in[14];
    const float* fb4 = (const float*)d_in[15];
    const float* fw5 = (const float*)d_in[16];
    const float* fb5 = (const float*)d_in[17];

    char* ws = (char*)d_ws;
    float* feat = (float*)ws;                                   // [64][7040]
    float* t1   = feat + (size_t)64 * 7040;                     // [64][3400]
    float* t2   = t1   + (size_t)64 * 3400;                     // [64][1000]
    float* t3   = t2   + (size_t)64 * 1000;                     // [64][500]
    float* o    = (float*)d_out;                                // [64][50]

    // bias pre-fill for all four FC outputs (316800 elems)
    fc_init<<<dim3(1238), dim3(256), 0, stream>>>(fb2, fb3, fb4, fb5, t1, t2, t3, o);

    lstm_kernel<<<dim3(440), dim3(256), 0, stream>>>(
        x1, x2, wx1, wh1, bx1, bh1, wx2, wh2, bx2, bh2, feat);

    // atomic split-K GEMMs (out pre-filled with bias)
    fc_gemm<<<dim3(54, 28), dim3(256), 0, stream>>>(feat, fw2, t1, 7040, 3400, 256);
    fc_gemm<<<dim3(16, 54), dim3(256), 0, stream>>>(t1, fw3, t2, 3400, 1000, 64);
    fc_gemm<<<dim3(8, 16), dim3(256), 0, stream>>>(t2, fw4, t3, 1000, 500, 64);
    fc_gemm<<<dim3(1, 16), dim3(256), 0, stream>>>(t3, fw5, o, 500, 50, 32);
}